// Round 12
// baseline (669.776 us; speedup 1.0000x reference)
//
#include <hip/hip_runtime.h>
#include <hip/hip_bf16.h>

#define NG 4
#define ID 128
#define HD 128
#define TH 384      // 3*HD
#define NB 32
#define NT 1000
#define XW (NG*ID)  // 512
#define OW (NG*HD)  // 512
// gi_ws layout, f16 units, per (b,g) region of NT*384:
//   t*384 + j*2     : r-gate (lo) | t*384 + j*2+1 : z-gate (hi)  (u32 pair)
//   t*384 + 256 + j : n-gate
// total 128 regions * 768KB = 98.304 MB.

typedef _Float16 v8h __attribute__((ext_vector_type(8)));
typedef __attribute__((ext_vector_type(4))) float v4f;

__device__ __forceinline__ float sigm(float v) {
    return __fdividef(1.f, 1.f + __expf(-v));
}
__device__ __forceinline__ float tanh_(float v) {
    v = fminf(fmaxf(v, -15.f), 15.f);
    float e2 = __expf(2.f * v);
    return __fdividef(e2 - 1.f, e2 + 1.f);
}
__device__ __forceinline__ float sel4(v4f a, int s) {
    float x01 = (s & 1) ? a[1] : a[0];
    float x23 = (s & 1) ? a[3] : a[2];
    return (s & 2) ? x23 : x01;
}

// ---------------- Phase 1 (R10-proven, unchanged): gi = x @ w_ih^T + b_ih.
// grid (3, 256, 4) [gate, b*8+ttile, g], block 256.
__global__ __launch_bounds__(256) void gi_gemm4(
    const float* __restrict__ x,
    const float* __restrict__ w_ih,
    const float* __restrict__ b_ih,
    _Float16* __restrict__ gi_ws)
{
    const int tid = threadIdx.x;
    const int w   = tid >> 6, l = tid & 63;
    const int lr  = l & 15, lq = l >> 4;
    const int g   = blockIdx.z;
    const int b   = blockIdx.y >> 3;
    const int tt  = blockIdx.y & 7;
    const int gate = blockIdx.x;
    const int n0  = gate * 128 + (w >> 1) * 64;
    const int t0  = tt * 128 + (w & 1) * 64;

    v4f acc[4][4];
    #pragma unroll
    for (int mi = 0; mi < 4; ++mi)
        #pragma unroll
        for (int ni = 0; ni < 4; ++ni)
            acc[mi][ni] = (v4f){0.f, 0.f, 0.f, 0.f};

    #pragma unroll
    for (int kf = 0; kf < 4; ++kf) {
        v8h bf[4], af[4];
        #pragma unroll
        for (int ni = 0; ni < 4; ++ni) {
            const float* p = &w_ih[(size_t)(g * TH + n0 + ni * 16 + lr) * ID + kf * 32 + lq * 8];
            float4 f0 = *reinterpret_cast<const float4*>(p);
            float4 f1 = *reinterpret_cast<const float4*>(p + 4);
            v8h v;
            v[0]=(_Float16)f0.x; v[1]=(_Float16)f0.y; v[2]=(_Float16)f0.z; v[3]=(_Float16)f0.w;
            v[4]=(_Float16)f1.x; v[5]=(_Float16)f1.y; v[6]=(_Float16)f1.z; v[7]=(_Float16)f1.w;
            bf[ni] = v;
        }
        #pragma unroll
        for (int mi = 0; mi < 4; ++mi) {
            int trow = t0 + mi * 16 + lr;
            int tl = trow < NT ? trow : NT - 1;
            const float* p = &x[((size_t)b * NT + tl) * XW + g * ID + kf * 32 + lq * 8];
            float4 f0 = *reinterpret_cast<const float4*>(p);
            float4 f1 = *reinterpret_cast<const float4*>(p + 4);
            v8h v;
            v[0]=(_Float16)f0.x; v[1]=(_Float16)f0.y; v[2]=(_Float16)f0.z; v[3]=(_Float16)f0.w;
            v[4]=(_Float16)f1.x; v[5]=(_Float16)f1.y; v[6]=(_Float16)f1.z; v[7]=(_Float16)f1.w;
            af[mi] = v;
        }
        #pragma unroll
        for (int mi = 0; mi < 4; ++mi)
            #pragma unroll
            for (int ni = 0; ni < 4; ++ni)
                acc[mi][ni] = __builtin_amdgcn_mfma_f32_16x16x32_f16(
                    af[mi], bf[ni], acc[mi][ni], 0, 0, 0);
    }

    const size_t rbase = (size_t)(b * NG + g) * NT;
    #pragma unroll
    for (int ni = 0; ni < 4; ++ni) {
        const int col = n0 + ni * 16 + lr;
        const float bias = b_ih[g * TH + col];
        const int jj = col & 127;
        const int off = (gate == 0) ? jj * 2 : (gate == 1) ? jj * 2 + 1 : 256 + jj;
        #pragma unroll
        for (int mi = 0; mi < 4; ++mi) {
            #pragma unroll
            for (int r = 0; r < 4; ++r) {
                const int t = t0 + mi * 16 + lq * 4 + r;
                if (t < NT)
                    gi_ws[(rbase + t) * 384 + off] = (_Float16)(acc[mi][ni][r] + bias);
            }
        }
    }
}

// ---------------- Phase 2: broadcast-B MFMA recurrence (R11 structure).
// R12: VMEM+unpack in ds_read shadow, 2-deep MFMA chains, pointer bumps,
// 1-step-deferred out store. Raw s_barrier; vmcnt never drained in-loop.
__global__ __launch_bounds__(512) void gru_recA(
    const _Float16* __restrict__ gi_ws,
    const float* __restrict__ w_hh,
    const float* __restrict__ b_hh,
    float* __restrict__ out)
{
    __shared__ __align__(16) _Float16 h_lds[2][128];

    const int tid = threadIdx.x;
    const int w = tid >> 6, l = tid & 63;
    const int lr = l & 15, lq = l >> 4;
    const int g = blockIdx.x & 3;
    const int b = blockIdx.x >> 2;

    // ---- w_hh A-frags (R10-proven): a[i][kf], rows i*128 + 16w + lr
    v8h a[3][4];
    #pragma unroll
    for (int i = 0; i < 3; ++i) {
        const int mrow = i * 128 + 16 * w + lr;
        #pragma unroll
        for (int kf = 0; kf < 4; ++kf) {
            const float* p = &w_hh[(size_t)(g * TH + mrow) * HD + kf * 32 + lq * 8];
            float4 f0 = *reinterpret_cast<const float4*>(p);
            float4 f1 = *reinterpret_cast<const float4*>(p + 4);
            v8h v;
            v[0]=(_Float16)f0.x; v[1]=(_Float16)f0.y; v[2]=(_Float16)f0.z; v[3]=(_Float16)f0.w;
            v[4]=(_Float16)f1.x; v[5]=(_Float16)f1.y; v[6]=(_Float16)f1.z; v[7]=(_Float16)f1.w;
            a[i][kf] = v;
        }
    }

    // ---- gate identity (R10-proven): j = 16w + 4*lq + sel; 4 copies, 1 active
    const int sel = l & 3;
    const int j   = 16 * w + 4 * lq + sel;
    const bool active = ((l >> 2) & 3) == 0;
    const v4f bv0 = *reinterpret_cast<const v4f*>(&b_hh[g * TH +       16 * w + 4 * lq]);
    const v4f bv1 = *reinterpret_cast<const v4f*>(&b_hh[g * TH + 128 + 16 * w + 4 * lq]);
    const v4f bv2 = *reinterpret_cast<const v4f*>(&b_hh[g * TH + 256 + 16 * w + 4 * lq]);
    const v4f zv  = (v4f){0.f, 0.f, 0.f, 0.f};
    float hprev = 0.f, pend = 0.f;
    float* ostore = out + (size_t)b * NT * OW + g * HD + j - OW;  // bumped before 1st store

    if (tid < 128) { h_lds[0][tid] = (_Float16)0.f; h_lds[1][tid] = (_Float16)0.f; }

    const char* gsrc = reinterpret_cast<const char*>(
        gi_ws + (size_t)(b * NG + g) * NT * 384);
    const int off_rz = j * 4;            // byte offset of (r,z) u32
    const int off_nv = 512 + j * 2;      // byte offset of n u16

    // ---- gi reg-ring, 2-step lead
    unsigned int rz0, rz1;
    _Float16 nv0, nv1;
    rz0 = *reinterpret_cast<const unsigned int*>(gsrc + off_rz);
    nv0 = *reinterpret_cast<const _Float16*>(gsrc + off_nv);
    rz1 = *reinterpret_cast<const unsigned int*>(gsrc + 768 + off_rz);
    nv1 = *reinterpret_cast<const _Float16*>(gsrc + 768 + off_nv);
    const char* pEb = gsrc + 2 * 768;    // even-step prefetch base (t+2)
    const char* pOb = gsrc + 3 * 768;    // odd-step prefetch base
    __syncthreads();   // once; drains prologue loads + LDS zero-init

#define MM(AC, I, K, F) AC = __builtin_amdgcn_mfma_f32_16x16x32_f16(a[I][K], F, AC, 0, 0, 0)

#define STEP(P, RZ, NV, PPTR, DO_PF, DO_ST)                                        \
    {                                                                              \
        const char* hb = reinterpret_cast<const char*>(&h_lds[P][0]) + lq * 16;    \
        v8h f0 = *reinterpret_cast<const v8h*>(hb);                                \
        v8h f2 = *reinterpret_cast<const v8h*>(hb + 128);                          \
        v8h f1 = *reinterpret_cast<const v8h*>(hb + 64);                           \
        v8h f3 = *reinterpret_cast<const v8h*>(hb + 192);                          \
        /* shadow: unpack current gi, store prev h, prefetch t+2 */                \
        float iR = (float)__builtin_bit_cast(_Float16, (unsigned short)(RZ & 0xffff)); \
        float iZ = (float)__builtin_bit_cast(_Float16, (unsigned short)(RZ >> 16));    \
        float iN = (float)NV;                                                      \
        if (DO_ST && active) *ostore = pend;                                       \
        ostore += OW;                                                              \
        if (DO_PF) {                                                               \
            RZ = *reinterpret_cast<const unsigned int*>(PPTR + off_rz);            \
            NV = *reinterpret_cast<const _Float16*>(PPTR + off_nv);                \
            PPTR += 1536;                                                          \
        }                                                                          \
        __builtin_amdgcn_sched_barrier(0);                                         \
        v4f c0a = bv0, c1a = bv1, c2a = bv2;                                       \
        v4f c0b = zv,  c1b = zv,  c2b = zv;                                        \
        MM(c0a, 0, 0, f0); MM(c1a, 1, 0, f0); MM(c2a, 2, 0, f0);                   \
        MM(c0b, 0, 2, f2); MM(c1b, 1, 2, f2); MM(c2b, 2, 2, f2);                   \
        MM(c0a, 0, 1, f1); MM(c1a, 1, 1, f1); MM(c2a, 2, 1, f1);                   \
        MM(c0b, 0, 3, f3); MM(c1b, 1, 3, f3); MM(c2b, 2, 3, f3);                   \
        v4f ac0 = c0a + c0b, ac1 = c1a + c1b, ac2 = c2a + c2b;                     \
        float ghr = sel4(ac0, sel);                                                \
        float ghz = sel4(ac1, sel);                                                \
        float ghn = sel4(ac2, sel);                                                \
        float rr = sigm(iR + ghr);                                                 \
        float zz = sigm(iZ + ghz);                                                 \
        float nn = tanh_(fmaf(rr, ghn, iN));                                       \
        float hn = fmaf(zz, hprev - nn, nn);                                       \
        hprev = hn;                                                                \
        pend = hn;                                                                 \
        if (active) h_lds[(P) ^ 1][j] = (_Float16)hn;                              \
        asm volatile("s_waitcnt lgkmcnt(0)" ::: "memory");                         \
        __builtin_amdgcn_s_barrier();                                              \
        __builtin_amdgcn_sched_barrier(0);                                         \
    }

    // peeled first pair (no store at t=0)
    STEP(0, rz0, nv0, pEb, 1, 0)
    STEP(1, rz1, nv1, pOb, 1, 1)
    // main loop t = 2 .. 997
    for (int t = 2; t < NT - 2; t += 2) {
        STEP(0, rz0, nv0, pEb, 1, 1)
        STEP(1, rz1, nv1, pOb, 1, 1)
    }
    // epilogue t = 998, 999 (no prefetch)
    STEP(0, rz0, nv0, pEb, 0, 1)
    STEP(1, rz1, nv1, pOb, 0, 1)
    // final flush: h(999)
    if (active) *ostore = pend;
#undef STEP
#undef MM
}

extern "C" void kernel_launch(void* const* d_in, const int* in_sizes, int n_in,
                              void* d_out, int out_size, void* d_ws, size_t ws_size,
                              hipStream_t stream) {
    const float* x    = (const float*)d_in[0];
    const float* w_ih = (const float*)d_in[1];
    const float* w_hh = (const float*)d_in[2];
    const float* b_ih = (const float*)d_in[3];
    const float* b_hh = (const float*)d_in[4];
    float* out = (float*)d_out;
    _Float16* gi_ws = (_Float16*)d_ws;   // 98.304 MB, layout above

    dim3 g1(3, NB * 8, NG);
    gi_gemm4<<<g1, 256, 0, stream>>>(x, w_ih, b_ih, gi_ws);
    gru_recA<<<NB * NG, 512, 0, stream>>>(gi_ws, w_hh, b_hh, out);
}

// Round 13
// 633.184 us; speedup vs baseline: 1.0578x; 1.0578x over previous
//
#include <hip/hip_runtime.h>
#include <hip/hip_bf16.h>

#define NG 4
#define ID 128
#define HD 128
#define TH 384      // 3*HD
#define NB 32
#define NT 1000
#define XW (NG*ID)  // 512
#define OW (NG*HD)  // 512
// gi_ws layout, f16 units, per (b,g) region of NT*384:
//   t*384 + j*2     : r-gate (lo) | t*384 + j*2+1 : z-gate (hi)  (u32 pair)
//   t*384 + 256 + j : n-gate
// total 128 regions * 768KB = 98.304 MB.

typedef _Float16 v8h __attribute__((ext_vector_type(8)));
typedef __attribute__((ext_vector_type(4))) float v4f;

__device__ __forceinline__ float sigm(float v) {
    return __fdividef(1.f, 1.f + __expf(-v));
}
__device__ __forceinline__ float tanh_(float v) {
    v = fminf(fmaxf(v, -15.f), 15.f);
    float e2 = __expf(2.f * v);
    return __fdividef(e2 - 1.f, e2 + 1.f);
}
__device__ __forceinline__ float sel4(v4f a, int s) {
    float x01 = (s & 1) ? a[1] : a[0];
    float x23 = (s & 1) ? a[3] : a[2];
    return (s & 2) ? x23 : x01;
}

// ---------------- Phase 1 (R10-proven, unchanged): gi = x @ w_ih^T + b_ih.
// grid (3, 256, 4) [gate, b*8+ttile, g], block 256.
__global__ __launch_bounds__(256) void gi_gemm4(
    const float* __restrict__ x,
    const float* __restrict__ w_ih,
    const float* __restrict__ b_ih,
    _Float16* __restrict__ gi_ws)
{
    const int tid = threadIdx.x;
    const int w   = tid >> 6, l = tid & 63;
    const int lr  = l & 15, lq = l >> 4;
    const int g   = blockIdx.z;
    const int b   = blockIdx.y >> 3;
    const int tt  = blockIdx.y & 7;
    const int gate = blockIdx.x;
    const int n0  = gate * 128 + (w >> 1) * 64;
    const int t0  = tt * 128 + (w & 1) * 64;

    v4f acc[4][4];
    #pragma unroll
    for (int mi = 0; mi < 4; ++mi)
        #pragma unroll
        for (int ni = 0; ni < 4; ++ni)
            acc[mi][ni] = (v4f){0.f, 0.f, 0.f, 0.f};

    #pragma unroll
    for (int kf = 0; kf < 4; ++kf) {
        v8h bf[4], af[4];
        #pragma unroll
        for (int ni = 0; ni < 4; ++ni) {
            const float* p = &w_ih[(size_t)(g * TH + n0 + ni * 16 + lr) * ID + kf * 32 + lq * 8];
            float4 f0 = *reinterpret_cast<const float4*>(p);
            float4 f1 = *reinterpret_cast<const float4*>(p + 4);
            v8h v;
            v[0]=(_Float16)f0.x; v[1]=(_Float16)f0.y; v[2]=(_Float16)f0.z; v[3]=(_Float16)f0.w;
            v[4]=(_Float16)f1.x; v[5]=(_Float16)f1.y; v[6]=(_Float16)f1.z; v[7]=(_Float16)f1.w;
            bf[ni] = v;
        }
        #pragma unroll
        for (int mi = 0; mi < 4; ++mi) {
            int trow = t0 + mi * 16 + lr;
            int tl = trow < NT ? trow : NT - 1;
            const float* p = &x[((size_t)b * NT + tl) * XW + g * ID + kf * 32 + lq * 8];
            float4 f0 = *reinterpret_cast<const float4*>(p);
            float4 f1 = *reinterpret_cast<const float4*>(p + 4);
            v8h v;
            v[0]=(_Float16)f0.x; v[1]=(_Float16)f0.y; v[2]=(_Float16)f0.z; v[3]=(_Float16)f0.w;
            v[4]=(_Float16)f1.x; v[5]=(_Float16)f1.y; v[6]=(_Float16)f1.z; v[7]=(_Float16)f1.w;
            af[mi] = v;
        }
        #pragma unroll
        for (int mi = 0; mi < 4; ++mi)
            #pragma unroll
            for (int ni = 0; ni < 4; ++ni)
                acc[mi][ni] = __builtin_amdgcn_mfma_f32_16x16x32_f16(
                    af[mi], bf[ni], acc[mi][ni], 0, 0, 0);
    }

    const size_t rbase = (size_t)(b * NG + g) * NT;
    #pragma unroll
    for (int ni = 0; ni < 4; ++ni) {
        const int col = n0 + ni * 16 + lr;
        const float bias = b_ih[g * TH + col];
        const int jj = col & 127;
        const int off = (gate == 0) ? jj * 2 : (gate == 1) ? jj * 2 + 1 : 256 + jj;
        #pragma unroll
        for (int mi = 0; mi < 4; ++mi) {
            #pragma unroll
            for (int r = 0; r < 4; ++r) {
                const int t = t0 + mi * 16 + lq * 4 + r;
                if (t < NT)
                    gi_ws[(rbase + t) * 384 + off] = (_Float16)(acc[mi][ni][r] + bias);
            }
        }
    }
}

// ---------------- Phase 2: broadcast-B MFMA recurrence (R11 step ordering).
// R13: out-stores batched in hv[8] regs (flush per 8 steps -> no store acks
// gating the in-order vmcnt waits for gi prefetch); 2-deep MFMA chains.
// Raw s_barrier + lgkmcnt(0) per step; vmcnt never drained in-loop.
__global__ __launch_bounds__(512) void gru_recB(
    const _Float16* __restrict__ gi_ws,
    const float* __restrict__ w_hh,
    const float* __restrict__ b_hh,
    float* __restrict__ out)
{
    __shared__ __align__(16) _Float16 h_lds[2][128];

    const int tid = threadIdx.x;
    const int w = tid >> 6, l = tid & 63;
    const int lr = l & 15, lq = l >> 4;
    const int g = blockIdx.x & 3;
    const int b = blockIdx.x >> 2;

    // ---- w_hh A-frags (R10-proven): a[i][kf], rows i*128 + 16w + lr
    v8h a[3][4];
    #pragma unroll
    for (int i = 0; i < 3; ++i) {
        const int mrow = i * 128 + 16 * w + lr;
        #pragma unroll
        for (int kf = 0; kf < 4; ++kf) {
            const float* p = &w_hh[(size_t)(g * TH + mrow) * HD + kf * 32 + lq * 8];
            float4 f0 = *reinterpret_cast<const float4*>(p);
            float4 f1 = *reinterpret_cast<const float4*>(p + 4);
            v8h v;
            v[0]=(_Float16)f0.x; v[1]=(_Float16)f0.y; v[2]=(_Float16)f0.z; v[3]=(_Float16)f0.w;
            v[4]=(_Float16)f1.x; v[5]=(_Float16)f1.y; v[6]=(_Float16)f1.z; v[7]=(_Float16)f1.w;
            a[i][kf] = v;
        }
    }

    // ---- gate identity (R10-proven): j = 16w + 4*lq + sel; 4 copies, 1 active
    const int sel = l & 3;
    const int j   = 16 * w + 4 * lq + sel;
    const bool active = ((l >> 2) & 3) == 0;
    const v4f bv0 = *reinterpret_cast<const v4f*>(&b_hh[g * TH +       16 * w + 4 * lq]);
    const v4f bv1 = *reinterpret_cast<const v4f*>(&b_hh[g * TH + 128 + 16 * w + 4 * lq]);
    const v4f bv2 = *reinterpret_cast<const v4f*>(&b_hh[g * TH + 256 + 16 * w + 4 * lq]);
    const v4f zv  = (v4f){0.f, 0.f, 0.f, 0.f};
    float hprev = 0.f;
    float* outp = out + (size_t)b * NT * OW + g * HD + j;

    if (tid < 128) { h_lds[0][tid] = (_Float16)0.f; h_lds[1][tid] = (_Float16)0.f; }

    const char* gsrc = reinterpret_cast<const char*>(
        gi_ws + (size_t)(b * NG + g) * NT * 384);
    const int off_rz = j * 4;            // byte offset of (r,z) u32
    const int off_nv = 512 + j * 2;      // byte offset of n u16

    // ---- gi reg-ring, 2-step lead (per parity)
    unsigned int rz0, rz1;
    _Float16 nv0, nv1;
    rz0 = *reinterpret_cast<const unsigned int*>(gsrc + off_rz);
    nv0 = *reinterpret_cast<const _Float16*>(gsrc + off_nv);
    rz1 = *reinterpret_cast<const unsigned int*>(gsrc + 768 + off_rz);
    nv1 = *reinterpret_cast<const _Float16*>(gsrc + 768 + off_nv);
    const char* pEb = gsrc + 2 * 768;    // even-step prefetch base (t+2)
    const char* pOb = gsrc + 3 * 768;    // odd-step prefetch base
    __syncthreads();   // once; drains prologue loads + LDS zero-init

#define MM(AC, I, K, F) AC = __builtin_amdgcn_mfma_f32_16x16x32_f16(a[I][K], F, AC, 0, 0, 0)

#define STEP(P, K, RZ, NV, PPTR, DO_PF)                                            \
    {                                                                              \
        const char* hb = reinterpret_cast<const char*>(&h_lds[P][0]) + lq * 16;    \
        v8h f0 = *reinterpret_cast<const v8h*>(hb);                                \
        v8h f2 = *reinterpret_cast<const v8h*>(hb + 128);                          \
        v8h f1 = *reinterpret_cast<const v8h*>(hb + 64);                           \
        v8h f3 = *reinterpret_cast<const v8h*>(hb + 192);                          \
        v4f c0a = bv0, c1a = bv1, c2a = bv2;                                       \
        v4f c0b = zv,  c1b = zv,  c2b = zv;                                        \
        MM(c0a, 0, 0, f0); MM(c1a, 1, 0, f0); MM(c2a, 2, 0, f0);                   \
        MM(c0b, 0, 2, f2); MM(c1b, 1, 2, f2); MM(c2b, 2, 2, f2);                   \
        MM(c0a, 0, 1, f1); MM(c1a, 1, 1, f1); MM(c2a, 2, 1, f1);                   \
        MM(c0b, 0, 3, f3); MM(c1b, 1, 3, f3); MM(c2b, 2, 3, f3);                   \
        v4f ac0 = c0a + c0b, ac1 = c1a + c1b, ac2 = c2a + c2b;                     \
        float ghr = sel4(ac0, sel);                                                \
        float ghz = sel4(ac1, sel);                                                \
        float ghn = sel4(ac2, sel);                                                \
        float iR = (float)__builtin_bit_cast(_Float16, (unsigned short)(RZ & 0xffff)); \
        float iZ = (float)__builtin_bit_cast(_Float16, (unsigned short)(RZ >> 16));    \
        float iN = (float)NV;                                                      \
        float rr = sigm(iR + ghr);                                                 \
        float zz = sigm(iZ + ghz);                                                 \
        float nn = tanh_(fmaf(rr, ghn, iN));                                       \
        float hn = fmaf(zz, hprev - nn, nn);                                       \
        hprev = hn;                                                                \
        hv[K] = hn;                                                                \
        if (active) h_lds[(P) ^ 1][j] = (_Float16)hn;                              \
        if (DO_PF) {                                                               \
            RZ = *reinterpret_cast<const unsigned int*>(PPTR + off_rz);            \
            NV = *reinterpret_cast<const _Float16*>(PPTR + off_nv);                \
            PPTR += 1536;                                                          \
        }                                                                          \
        asm volatile("s_waitcnt lgkmcnt(0)" ::: "memory");                         \
        __builtin_amdgcn_s_barrier();                                              \
        __builtin_amdgcn_sched_barrier(0);                                         \
    }

    float hv[8];
    for (int T = 0; T < 125; ++T) {
        const bool pfT = (T < 124);     // steps 998,999 have no t+2 to fetch
        STEP(0, 0, rz0, nv0, pEb, true)
        STEP(1, 1, rz1, nv1, pOb, true)
        STEP(0, 2, rz0, nv0, pEb, true)
        STEP(1, 3, rz1, nv1, pOb, true)
        STEP(0, 4, rz0, nv0, pEb, true)
        STEP(1, 5, rz1, nv1, pOb, true)
        STEP(0, 6, rz0, nv0, pEb, pfT)
        STEP(1, 7, rz1, nv1, pOb, pfT)
        if (active) {
            #pragma unroll
            for (int k2 = 0; k2 < 8; ++k2)
                outp[(size_t)k2 * OW] = hv[k2];
        }
        outp += 8 * (size_t)OW;
    }
#undef STEP
#undef MM
}

extern "C" void kernel_launch(void* const* d_in, const int* in_sizes, int n_in,
                              void* d_out, int out_size, void* d_ws, size_t ws_size,
                              hipStream_t stream) {
    const float* x    = (const float*)d_in[0];
    const float* w_ih = (const float*)d_in[1];
    const float* w_hh = (const float*)d_in[2];
    const float* b_ih = (const float*)d_in[3];
    const float* b_hh = (const float*)d_in[4];
    float* out = (float*)d_out;
    _Float16* gi_ws = (_Float16*)d_ws;   // 98.304 MB, layout above

    dim3 g1(3, NB * 8, NG);
    gi_gemm4<<<g1, 256, 0, stream>>>(x, w_ih, b_ih, gi_ws);
    gru_recB<<<NB * NG, 512, 0, stream>>>(gi_ws, w_hh, b_hh, out);
}